// Round 1
// baseline (849.260 us; speedup 1.0000x reference)
//
#include <hip/hip_runtime.h>
#include <math.h>

#define NLAYER 3
#define LREADx 512
#define NROWSx 65536   // 128*512
#define NSEQx  96

__device__ __forceinline__ float fsigmoid(float v){ return 1.f/(1.f+__expf(-v)); }
__device__ __forceinline__ float fsoftplus(float v){ return fmaxf(v,0.f) + __logf(1.f + __expf(-fabsf(v))); }

template<int CTRL>
__device__ __forceinline__ float dpp_add(float v){
  int x = __builtin_amdgcn_update_dpp(0, __float_as_int(v), CTRL, 0xF, 0xF, false);
  return v + __int_as_float(x);
}

// ---------------- expander: h = reads @ ew.T + eb ----------------
__global__ __launch_bounds__(256) void k_exp(const float* __restrict__ reads,
    const float* __restrict__ ew, const float* __restrict__ eb, float* __restrict__ h){
  int idx = blockIdx.x*256 + threadIdx.x;     // NROWS*64
  int d = idx & 63;
  int row = idx >> 6;
  float4 r4 = *(const float4*)(reads + (size_t)row*4);
  float4 w4 = *(const float4*)(ew + d*4);
  h[idx] = fmaf(r4.x,w4.x, fmaf(r4.y,w4.y, fmaf(r4.z,w4.z, fmaf(r4.w,w4.w, eb[d]))));
}

// ---------------- in_proj: xz = h @ inw.T ; split x_pre / silu(z) ----------------
// block 256 threads = 256 output cols, 32 rows/block (uniform row loop -> s_load h row)
__global__ __launch_bounds__(256) void k_xz(const float* __restrict__ h,
    const float* __restrict__ w, float* __restrict__ xpre, float* __restrict__ zsil){
  int j = threadIdx.x;
  int row0 = blockIdx.x*32;
  float4 wr[16];
  #pragma unroll
  for (int k=0;k<16;k++) wr[k] = *(const float4*)(w + j*64 + k*4);
  for (int r=0;r<32;r++){
    const float4* hr = (const float4*)(h + (size_t)(row0+r)*64);
    float a = 0.f;
    #pragma unroll
    for (int k=0;k<16;k++){
      float4 hv = hr[k];
      a = fmaf(hv.x,wr[k].x, fmaf(hv.y,wr[k].y, fmaf(hv.z,wr[k].z, fmaf(hv.w,wr[k].w, a))));
    }
    size_t o = (size_t)(row0+r)*128;
    if (j < 128) xpre[o + j] = a;
    else         zsil[o + j - 128] = a * fsigmoid(a);
  }
}

// ---------------- causal depthwise conv (k=4) + silu ----------------
__global__ __launch_bounds__(256) void k_conv(const float* __restrict__ xpre,
    const float* __restrict__ cw, const float* __restrict__ cb, float* __restrict__ x){
  int idx = blockIdx.x*256 + threadIdx.x;     // b*L*128 flat
  int d = idx & 127;
  int l = (idx >> 7) & 511;
  float4 w4 = *(const float4*)(cw + d*4);
  const float* base = xpre + idx;
  float v0 = (l>=3) ? base[-3*128] : 0.f;
  float v1 = (l>=2) ? base[-2*128] : 0.f;
  float v2 = (l>=1) ? base[-1*128] : 0.f;
  float v3 = base[0];
  float a = fmaf(v0,w4.x, fmaf(v1,w4.y, fmaf(v2,w4.z, fmaf(v3,w4.w, cb[d]))));
  x[idx] = a * fsigmoid(a);
}

// ---------------- x_proj (K=128,N=36) + dt=softplus(..) + B/C interleave ----------------
// thread-per-row, xwT rows are wave-uniform -> s_load
__global__ __launch_bounds__(256) void k_xd(const float* __restrict__ x,
    const float* __restrict__ xwT, const float* __restrict__ dtw,
    const float* __restrict__ dtb, float* __restrict__ dt, float* __restrict__ bc){
  __shared__ float4 xd03[256];
  __shared__ float  bcs[256][33];
  int t = threadIdx.x;
  int row = blockIdx.x*256 + t;
  float acc[36];
  #pragma unroll
  for (int c=0;c<36;c++) acc[c]=0.f;
  const float4* xr = (const float4*)(x + (size_t)row*128);
  for (int k4=0;k4<32;k4++){
    float4 xv = xr[k4];
    float xa[4] = {xv.x, xv.y, xv.z, xv.w};
    #pragma unroll
    for (int kk=0;kk<4;kk++){
      const float* wk = xwT + (k4*4+kk)*36;   // uniform -> SMEM
      #pragma unroll
      for (int c=0;c<36;c++) acc[c] = fmaf(xa[kk], wk[c], acc[c]);
    }
  }
  xd03[t] = make_float4(acc[0],acc[1],acc[2],acc[3]);
  #pragma unroll
  for (int nn=0;nn<16;nn++){ bcs[t][2*nn] = acc[4+nn]; bcs[t][2*nn+1] = acc[20+nn]; }
  __syncthreads();
  int d = t & 127, half = t >> 7;
  float4 w4 = *(const float4*)(dtw + d*4);
  float bv = dtb[d];
  size_t row0 = (size_t)blockIdx.x*256;
  for (int rr=half; rr<256; rr+=2){
    float4 s4 = xd03[rr];
    float v = fmaf(s4.x,w4.x, fmaf(s4.y,w4.y, fmaf(s4.z,w4.z, fmaf(s4.w,w4.w, bv))));
    dt[(row0+rr)*128 + d] = fsoftplus(v);
  }
  for (int i=t; i<256*32; i+=256){
    int r = i >> 5, cc = i & 31;
    bc[(row0+r)*32 + cc] = bcs[r][cc];
  }
}

// ---------------- selective scan ----------------
// block = (b, d-group of 16). thread = (d_local, n). state h in 1 VGPR.
// y = ((sum_n h*C) + x*D) * silu(z), fused epilogue, written to y buffer.
__global__ __launch_bounds__(256) void k_scan(const float* __restrict__ dt,
    const float* __restrict__ x, const float* __restrict__ zsil,
    const float* __restrict__ bc, const float* __restrict__ alog,
    const float* __restrict__ Dp, float* __restrict__ y){
  __shared__ float2 dd[64*16];
  __shared__ float2 bcs[64*16];
  __shared__ float  xs[64*16];
  __shared__ float  zss[64*16];
  __shared__ float  ys[64*16];
  int t = threadIdx.x;
  int b  = blockIdx.x >> 3;
  int dg = blockIdx.x & 7;
  int dl = t >> 4, n = t & 15;
  float aL = -__expf(alog[(dg*16+dl)*16 + n]) * 1.44269504f;   // A * log2(e)
  float Dv = Dp[dg*16 + (t & 15)];
  float hs = 0.f;
  int lt = t >> 2, q = t & 3;
  size_t rowbase = ((size_t)b*LREADx)*128 + dg*16;
  size_t bcbase  = ((size_t)b*LREADx)*32;
  for (int c=0;c<8;c++){
    int l0 = c*64;
    { // stage 64 timesteps
      size_t g = rowbase + (size_t)(l0+lt)*128 + q*4;
      float4 d4 = *(const float4*)(dt + g);
      float4 x4 = *(const float4*)(x + g);
      float4 z4 = *(const float4*)(zsil + g);
      int e = lt*16 + q*4;
      dd[e+0] = make_float2(d4.x, d4.x*x4.x);
      dd[e+1] = make_float2(d4.y, d4.y*x4.y);
      dd[e+2] = make_float2(d4.z, d4.z*x4.z);
      dd[e+3] = make_float2(d4.w, d4.w*x4.w);
      *(float4*)(xs+e)  = x4;
      *(float4*)(zss+e) = z4;
      size_t gb = bcbase + (size_t)(l0+lt)*32 + q*4;
      float4 b0 = *(const float4*)(bc + gb);
      float4 b1 = *(const float4*)(bc + gb + 16);
      *(float4*)((float*)bcs + lt*32 + q*4)      = b0;
      *(float4*)((float*)bcs + lt*32 + 16 + q*4) = b1;
    }
    __syncthreads();
    #pragma unroll 4
    for (int l=0;l<64;l++){
      float2 dv = dd[l*16 + dl];
      float2 bv = bcs[l*16 + n];
      float e = exp2f(dv.x * aL);
      hs = fmaf(e, hs, dv.y * bv.x);
      float p = hs * bv.y;
      p = dpp_add<0x121>(p);   // row_ror:1
      p = dpp_add<0x122>(p);   // row_ror:2
      p = dpp_add<0x124>(p);   // row_ror:4
      p = dpp_add<0x128>(p);   // row_ror:8
      if (n == 0) ys[l*16 + dl] = p;
    }
    __syncthreads();
    #pragma unroll
    for (int i=0;i<4;i++){
      int idx = t + i*256;
      float v = (ys[idx] + xs[idx]*Dv) * zss[idx];
      int le = idx >> 4, de = idx & 15;
      y[rowbase + (size_t)(l0+le)*128 + de] = v;
    }
    __syncthreads();
  }
}

// ---------------- out proj + LayerNorm + ReLU ----------------
// 1-wave blocks: 64 cols, 8 rows/block; y rows uniform -> s_load; LN via wave shuffles
__global__ __launch_bounds__(64) void k_out(const float* __restrict__ y,
    const float* __restrict__ ow, const float* __restrict__ lnw,
    const float* __restrict__ lnb, float* __restrict__ h){
  int j = threadIdx.x;
  int row0 = blockIdx.x*8;
  float acc[8];
  #pragma unroll
  for (int r=0;r<8;r++) acc[r]=0.f;
  for (int k=0;k<32;k++){
    float4 w4 = *(const float4*)(ow + j*128 + k*4);
    #pragma unroll
    for (int r=0;r<8;r++){
      float4 yv = *(const float4*)(y + (size_t)(row0+r)*128 + k*4);  // uniform -> SMEM
      acc[r] = fmaf(yv.x,w4.x, fmaf(yv.y,w4.y, fmaf(yv.z,w4.z, fmaf(yv.w,w4.w, acc[r]))));
    }
  }
  float lw = lnw[j], lb = lnb[j];
  #pragma unroll
  for (int r=0;r<8;r++){
    float v = acc[r];
    float s = v;
    #pragma unroll
    for (int off=1;off<64;off<<=1) s += __shfl_xor(s, off, 64);
    float m = s * (1.f/64.f);
    float dv = v - m;
    float s2 = dv*dv;
    #pragma unroll
    for (int off=1;off<64;off<<=1) s2 += __shfl_xor(s2, off, 64);
    float o = dv * rsqrtf(s2*(1.f/64.f) + 1e-5f) * lw + lb;
    h[(size_t)(row0+r)*64 + j] = fmaxf(o, 0.f);
  }
}

// ---------------- mean + last pooling -> enc ----------------
__global__ __launch_bounds__(64) void k_pool(const float* __restrict__ h, float* __restrict__ enc){
  int b = blockIdx.x, d = threadIdx.x;
  const float* hb = h + (size_t)b*LREADx*64 + d;
  float s = 0.f;
  for (int l=0;l<LREADx;l++) s += hb[(size_t)l*64];
  enc[b*128 + d]      = s * (1.f/512.f);
  enc[b*128 + 64 + d] = hb[(size_t)511*64];
}

// ---------------- q,k projections ----------------
__global__ __launch_bounds__(256) void k_qk(const float* __restrict__ enc,
    const int* __restrict__ sidx, const float* __restrict__ qw, const float* __restrict__ qb,
    const float* __restrict__ kw, const float* __restrict__ kb,
    float* __restrict__ qbuf, float* __restrict__ kbuf){
  int idx = blockIdx.x*256 + threadIdx.x;   // 96*64 q outputs then 128*64 k outputs
  if (idx < NSEQx*64){
    int qi = idx >> 6, j = idx & 63;
    const float* er = enc + (size_t)sidx[qi]*128;
    const float* wr = qw + j*128;
    float a = qb[j];
    for (int k=0;k<32;k++){
      float4 e4 = *(const float4*)(er + k*4);
      float4 w4 = *(const float4*)(wr + k*4);
      a = fmaf(e4.x,w4.x, fmaf(e4.y,w4.y, fmaf(e4.z,w4.z, fmaf(e4.w,w4.w, a))));
    }
    qbuf[idx] = a;
  } else {
    int i2 = idx - NSEQx*64;
    int ki = i2 >> 6, j = i2 & 63;
    const float* er = enc + (size_t)ki*128;
    const float* wr = kw + j*128;
    float a = kb[j];
    for (int k=0;k<32;k++){
      float4 e4 = *(const float4*)(er + k*4);
      float4 w4 = *(const float4*)(wr + k*4);
      a = fmaf(e4.x,w4.x, fmaf(e4.y,w4.y, fmaf(e4.z,w4.z, fmaf(e4.w,w4.w, a))));
    }
    kbuf[i2] = a;
  }
}

// ---------------- scores: qk^T per head, relu, mix, max ----------------
__global__ __launch_bounds__(256) void k_score(const float* __restrict__ qbuf,
    const float* __restrict__ kbuf, const float* __restrict__ mixw,
    const float* __restrict__ mixb, float* __restrict__ out){
  int idx = blockIdx.x*256 + threadIdx.x;   // 96*128
  int ki = idx & 127, qi = idx >> 7;
  const float* qr = qbuf + qi*64;
  const float* kr = kbuf + ki*64;
  float s[4];
  #pragma unroll
  for (int hh=0;hh<4;hh++){
    float a = 0.f;
    #pragma unroll
    for (int k=0;k<4;k++){
      float4 q4 = *(const float4*)(qr + hh*16 + k*4);
      float4 k4 = *(const float4*)(kr + hh*16 + k*4);
      a = fmaf(q4.x,k4.x, fmaf(q4.y,k4.y, fmaf(q4.z,k4.z, fmaf(q4.w,k4.w, a))));
    }
    s[hh] = fmaxf(a, 0.f);
  }
  float best = -1e30f;
  #pragma unroll
  for (int hh=0;hh<4;hh++){
    float v = mixb[hh];
    #pragma unroll
    for (int h2=0;h2<4;h2++) v = fmaf(s[h2], mixw[hh*4+h2], v);
    best = fmaxf(best, v);
  }
  out[idx] = best;
}

// ---------------- transpose x_proj_w once ----------------
__global__ __launch_bounds__(256) void k_trans(const float* __restrict__ xw, float* __restrict__ xwT){
  int i = threadIdx.x + blockIdx.x*256;
  if (i < NLAYER*36*128){
    int l = i / 4608, rem = i % 4608;
    int c = rem >> 7, k = rem & 127;
    xwT[l*4608 + k*36 + c] = xw[i];
  }
}

extern "C" void kernel_launch(void* const* d_in, const int* in_sizes, int n_in,
                              void* d_out, int out_size, void* d_ws, size_t ws_size,
                              hipStream_t stream) {
  (void)in_sizes; (void)n_in; (void)out_size; (void)ws_size;
  const float* reads = (const float*)d_in[0];
  const int*   sidx  = (const int*)d_in[1];
  const float* ew    = (const float*)d_in[2];
  const float* eb    = (const float*)d_in[3];
  const float* inw   = (const float*)d_in[4];
  const float* cw    = (const float*)d_in[5];
  const float* cb    = (const float*)d_in[6];
  const float* xw    = (const float*)d_in[7];
  const float* dtw   = (const float*)d_in[8];
  const float* dtb   = (const float*)d_in[9];
  const float* alog  = (const float*)d_in[10];
  const float* Dp    = (const float*)d_in[11];
  const float* ow    = (const float*)d_in[12];
  const float* lnw   = (const float*)d_in[13];
  const float* lnb   = (const float*)d_in[14];
  const float* qw    = (const float*)d_in[15];
  const float* qb    = (const float*)d_in[16];
  const float* kw    = (const float*)d_in[17];
  const float* kb    = (const float*)d_in[18];
  const float* mixw  = (const float*)d_in[19];
  const float* mixb  = (const float*)d_in[20];

  float* ws  = (float*)d_ws;
  float* h   = ws;                 // 4,194,304
  float* yx  = ws + 4194304;       // 8,388,608 (x_pre, later reused as y)
  float* zs  = ws + 12582912;      // 8,388,608
  float* x   = ws + 20971520;      // 8,388,608
  float* dt  = ws + 29360128;      // 8,388,608
  float* bc  = ws + 37748736;      // 2,097,152
  float* enc = ws + 39845888;      // 16,384
  float* qk  = ws + 39862272;      // 6144 + 8192
  float* xwT = ws + 39876608;      // 13,824

  k_trans<<<54, 256, 0, stream>>>(xw, xwT);
  k_exp<<<16384, 256, 0, stream>>>(reads, ew, eb, h);
  for (int l = 0; l < NLAYER; l++){
    k_xz  <<<2048, 256, 0, stream>>>(h, inw + l*16384, yx, zs);
    k_conv<<<32768, 256, 0, stream>>>(yx, cw + l*512, cb + l*128, x);
    k_xd  <<<256, 256, 0, stream>>>(x, xwT + l*4608, dtw + l*512, dtb + l*128, dt, bc);
    k_scan<<<1024, 256, 0, stream>>>(dt, x, zs, bc, alog + l*2048, Dp + l*128, yx);
    k_out <<<8192, 64, 0, stream>>>(yx, ow + l*8192, lnw + l*64, lnb + l*64, h);
  }
  k_pool <<<128, 64, 0, stream>>>(h, enc);
  k_qk   <<<56, 256, 0, stream>>>(enc, sidx, qw, qb, kw, kb, qk, qk + 6144);
  k_score<<<48, 256, 0, stream>>>(qk, qk + 6144, mixw, mixb, (float*)d_out);
}